// Round 4
// baseline (84.235 us; speedup 1.0000x reference)
//
#include <hip/hip_runtime.h>
#include <hip/hip_bf16.h>

#define N      8192
#define D_IN   30
#define HID    32
#define D_OUT  30
#define FFD    128
#define ZC     34

typedef __attribute__((ext_vector_type(8))) short short8;
typedef __attribute__((ext_vector_type(16))) float f32x16;
typedef __attribute__((ext_vector_type(2))) float f32x2;

static __device__ __forceinline__ ushort f2bf(float x) {
    uint32_t u = __float_as_uint(x);
    uint32_t r = (u + 0x7fffu + ((u >> 16) & 1u)) >> 16;   // RTNE
    return (ushort)r;
}

// ---------------------------------------------------------------------------
// Kernel A: QKV projections -> bf16, V transposed to Vt[32][N], and
// P' = (sqrt(2c)*p, -c*|p|^2) with c = log2e/(2*sigma^2). Q pre-scaled by
// log2e/sqrt(HID) so the QK MFMA output is directly the exp2 exponent.
// ---------------------------------------------------------------------------
__global__ __launch_bounds__(256) void dv_qkv_kernel(
    const float* __restrict__ Z,
    const float* __restrict__ Wq, const float* __restrict__ bq,
    const float* __restrict__ Wk, const float* __restrict__ bk,
    const float* __restrict__ Wv, const float* __restrict__ bv,
    ushort* __restrict__ Qb, ushort* __restrict__ Kb,
    ushort* __restrict__ Vt, float4* __restrict__ Pg)
{
    __shared__ ushort sv[8][33];
    const int t = blockIdx.x * 256 + threadIdx.x;
    const int i = t >> 5;
    const int h = t & 31;
    const float* z = Z + (size_t)i * ZC;

    float q = bq[h], k = bk[h], v = bv[h];
#pragma unroll
    for (int d = 0; d < D_IN; ++d) {
        float zf = z[d];
        q = fmaf(zf, Wq[d * HID + h], q);
        k = fmaf(zf, Wk[d * HID + h], k);
        v = fmaf(zf, Wv[d * HID + h], v);
    }
    const float QS = 0.17677669529663687f * 1.4426950408889634f; // log2e/sqrt(32)
    Qb[(size_t)i * HID + h] = f2bf(q * QS);
    Kb[(size_t)i * HID + h] = f2bf(k);
    sv[threadIdx.x >> 5][h] = f2bf(v);

    if (h == 0) {
        float p0 = z[D_IN], p1 = z[D_IN + 1], p2 = z[D_IN + 2];
        const float C2 = 1.4426950408889634f / 0.18f;   // log2e/(2*sigma^2)
        const float SC = sqrtf(2.0f * C2);
        float4 pp;
        pp.x = p0 * SC; pp.y = p1 * SC; pp.z = p2 * SC;
        pp.w = -C2 * (p0 * p0 + p1 * p1 + p2 * p2);
        Pg[i] = pp;
    }
    __syncthreads();
    const int ho = threadIdx.x >> 3, io = threadIdx.x & 7;
    const int i0 = blockIdx.x * 8;
    Vt[(size_t)ho * N + i0 + io] = sv[io][ho];
}

// ---------------------------------------------------------------------------
// Kernel B: fused MFMA attention (k-mapping-agnostic PV, see R3 notes).
// Grid = 64 row-blocks x JG. 4 waves/block, wave owns 32 i-rows.
// Gate arithmetic packed as f32x2 (v_pk_fma_f32) over j-pairs; P staged SoA.
// ---------------------------------------------------------------------------
__global__ __launch_bounds__(256, 2) void dv_attn_kernel(
    const ushort* __restrict__ Qb, const ushort* __restrict__ Kb,
    const ushort* __restrict__ Vt, const float4* __restrict__ Pg,
    float* __restrict__ partial, int nch)
{
    __shared__ ushort lK[128 * 32];   // K tile, 16B-chunk rot swizzle c'=(c+(j>>1))&3
    __shared__ ushort lV[32 * 128];   // V^T tile, 8B-chunk XOR swizzle c'=c^h
    __shared__ float lPx[128], lPy[128], lPz[128], lPw[128];

    const int tid  = threadIdx.x;
    const int lane = tid & 63;
    const int wv   = tid >> 6;
    const int h2   = lane >> 5;
    const int l31  = lane & 31;
    const int rb   = blockIdx.x & 63;
    const int jg   = blockIdx.x >> 6;
    const int i0w  = rb * 128 + wv * 32;

    const ushort* qp = Qb + (size_t)(i0w + l31) * HID + h2 * 8;
    const short8 qf0 = *(const short8*)qp;
    const short8 qf1 = *(const short8*)(qp + 16);
    const float4 psi = Pg[i0w + l31];
    const f32x2 psix = {psi.x, psi.x};
    const f32x2 psiy = {psi.y, psi.y};
    const f32x2 psiz = {psi.z, psi.z};
    const f32x2 psiw = {psi.w, psi.w};

    f32x16 zacc, oacc;
#pragma unroll
    for (int r = 0; r < 16; ++r) { zacc[r] = 0.f; oacc[r] = 0.f; }
    float ssA = 0.f, ssB = 0.f;

    const int cA0 = (h2 + (l31 >> 1)) & 3;
    const int cA1 = (cA0 + 2) & 3;

    for (int ch = 0; ch < nch; ++ch) {
        const int j0 = (jg * nch + ch) << 7;
        __syncthreads();
        {
            int idx = tid;
#pragma unroll
            for (int rep = 0; rep < 2; ++rep, idx += 256) {
                int jr = idx >> 2, c = idx & 3;
                int c2 = (c + (jr >> 1)) & 3;
                *(uint4*)&lK[jr * 32 + c2 * 8] =
                    *(const uint4*)&Kb[(size_t)(j0 + jr) * HID + c * 8];
            }
            idx = tid;
#pragma unroll
            for (int rep = 0; rep < 4; ++rep, idx += 256) {
                int hh = idx >> 5, cc = idx & 31;
                int cs = cc ^ hh;
                *(uint2*)&lV[hh * 128 + cs * 4] =
                    *(const uint2*)&Vt[(size_t)hh * N + j0 + cc * 4];
            }
            if (tid < 128) {
                float4 pp = Pg[j0 + tid];
                lPx[tid] = pp.x; lPy[tid] = pp.y;
                lPz[tid] = pp.z; lPw[tid] = pp.w;
            }
        }
        __syncthreads();

#pragma unroll
        for (int t32 = 0; t32 < 4; ++t32) {
            const ushort* krow = &lK[(t32 * 32 + l31) * 32];
            short8 kf0 = *(const short8*)&krow[cA0 * 8];
            short8 kf1 = *(const short8*)&krow[cA1 * 8];
            f32x16 s = __builtin_amdgcn_mfma_f32_32x32x16_bf16(kf0, qf0, zacc, 0, 0, 0);
            s = __builtin_amdgcn_mfma_f32_32x32x16_bf16(kf1, qf1, s, 0, 0, 0);

            const int pb = t32 * 32 + h2 * 4;
            uint32_t pk[8];
#pragma unroll
            for (int p = 0; p < 8; ++p) {
                const int jb = pb + ((2 * p) & 3) + 8 * (p >> 1);
                f32x2 px = *(const f32x2*)&lPx[jb];
                f32x2 py = *(const f32x2*)&lPy[jb];
                f32x2 pz = *(const f32x2*)&lPz[jb];
                f32x2 pw = *(const f32x2*)&lPw[jb];
                f32x2 tt = __builtin_elementwise_fma(px, psix, pw);
                tt = __builtin_elementwise_fma(py, psiy, tt);
                tt = __builtin_elementwise_fma(pz, psiz, tt);
                tt = tt + psiw;                         // = -D (<= 0 + eps)
                f32x2 sp = {s[2 * p], s[2 * p + 1]};
                f32x2 ts = tt + sp;                     // = S' - D
                float e0a = __builtin_amdgcn_exp2f(-tt[0]);   // 2^D
                float e0b = __builtin_amdgcn_exp2f(-ts[0]);   // 2^(D-S')
                float a0  = __builtin_amdgcn_rcpf(e0a + e0b);
                float e1a = __builtin_amdgcn_exp2f(-tt[1]);
                float e1b = __builtin_amdgcn_exp2f(-ts[1]);
                float a1  = __builtin_amdgcn_rcpf(e1a + e1b);
                ssA += a0;
                ssB += a1;
                asm("v_cvt_pk_bf16_f32 %0, %1, %2" : "=v"(pk[p]) : "v"(a0), "v"(a1));
            }
            union BV { uint32_t u[4]; short8 v; };
            BV fa, fb;
            fa.u[0] = pk[0]; fa.u[1] = pk[1]; fa.u[2] = pk[2]; fa.u[3] = pk[3];
            fb.u[0] = pk[4]; fb.u[1] = pk[5]; fb.u[2] = pk[6]; fb.u[3] = pk[7];

            // B-fragments: V rows through the SAME j-permutation as fa/fb.
            const ushort* vrow = &lV[l31 * 128];
            const int cb = t32 * 8 + h2;
            BV b0, b1;
            *(uint2*)&b0.u[0] = *(const uint2*)&vrow[((cb    ) ^ l31) * 4];
            *(uint2*)&b0.u[2] = *(const uint2*)&vrow[((cb + 2) ^ l31) * 4];
            *(uint2*)&b1.u[0] = *(const uint2*)&vrow[((cb + 4) ^ l31) * 4];
            *(uint2*)&b1.u[2] = *(const uint2*)&vrow[((cb + 6) ^ l31) * 4];

            oacc = __builtin_amdgcn_mfma_f32_32x32x16_bf16(fa.v, b0.v, oacc, 0, 0, 0);
            oacc = __builtin_amdgcn_mfma_f32_32x32x16_bf16(fb.v, b1.v, oacc, 0, 0, 0);
        }
    }

    float ssum = ssA + ssB;
    float sst = ssum + __shfl_xor(ssum, 32, 64);
    const size_t pbase = (size_t)jg * N * 33;
    if (lane < 32)
        partial[pbase + (size_t)(i0w + lane) * 33 + 32] = sst;
#pragma unroll
    for (int r = 0; r < 16; ++r) {
        int ir = (r & 3) + 8 * (r >> 2) + 4 * h2 + i0w;
        partial[pbase + (size_t)ir * 33 + l31] = oacc[r];
    }
}

// ---------------------------------------------------------------------------
// Kernel C: reduce JG partials + full epilogue. 512 blocks x 256 thr,
// 16 rows/block, 16 threads per row (grp = tid>>4 picks output/FF slice).
// ---------------------------------------------------------------------------
__global__ __launch_bounds__(256) void dv_epilogue_kernel(
    const float* __restrict__ partial, int JG,
    const float* __restrict__ Wo, const float* __restrict__ bo,
    const float* __restrict__ ln_g, const float* __restrict__ ln_b,
    const float* __restrict__ W1, const float* __restrict__ b1,
    const float* __restrict__ W2, const float* __restrict__ b2,
    const float* __restrict__ We, const float* __restrict__ be,
    float* __restrict__ out)
{
    __shared__ float red[33][16];
    __shared__ float Hl[D_OUT][16];
    __shared__ float Hnl[D_OUT][16];
    __shared__ float red2[D_OUT][256];
    __shared__ float r2s[D_OUT][16];
    __shared__ float mvl[2][16];
    __shared__ float ker[16][16];

    const int tid  = threadIdx.x;
    const int row0 = blockIdx.x * 16;

    for (int idx = tid; idx < 33 * 16; idx += 256) {
        int il = idx / 33, c = idx - il * 33;
        float s = 0.f;
        for (int jg = 0; jg < JG; ++jg)
            s += partial[((size_t)jg * N + row0 + il) * 33 + c];
        red[c][il] = s;
    }
    __syncthreads();

    const int il = tid & 15, grp = tid >> 4;
    const int o0 = grp * 2;
    {
        float inv = __builtin_amdgcn_rcpf(red[32][il] + 1e-8f);
        if (grp < 15) {
#pragma unroll
            for (int oo = 0; oo < 2; ++oo) {
                int o = o0 + oo;
                float acc = 0.f;
#pragma unroll
                for (int h = 0; h < HID; ++h)
                    acc = fmaf(red[h][il], Wo[h * D_OUT + o], acc);
                Hl[o][il] = fmaf(inv, acc, bo[o]);
            }
        }
    }
    __syncthreads();
    if (tid < 16) {
        float mu = 0.f;
#pragma unroll
        for (int o = 0; o < D_OUT; ++o) mu += Hl[o][tid];
        mu *= (1.0f / D_OUT);
        float var = 0.f;
#pragma unroll
        for (int o = 0; o < D_OUT; ++o) { float d = Hl[o][tid] - mu; var = fmaf(d, d, var); }
        var *= (1.0f / D_OUT);
        mvl[0][tid] = mu;
        mvl[1][tid] = rsqrtf(var + 1e-5f);
    }
    __syncthreads();
    if (grp < 15) {
        float mu = mvl[0][il], rs = mvl[1][il];
#pragma unroll
        for (int oo = 0; oo < 2; ++oo) {
            int o = o0 + oo;
            Hnl[o][il] = fmaf((Hl[o][il] - mu) * rs, ln_g[o], ln_b[o]);
        }
    }
    __syncthreads();
    {
        float o2[D_OUT];
#pragma unroll
        for (int o = 0; o < D_OUT; ++o) o2[o] = 0.f;
        const int f0 = grp * 8;
        for (int f = f0; f < f0 + 8; ++f) {
            float acc = b1[f];
#pragma unroll
            for (int o = 0; o < D_OUT; ++o)
                acc = fmaf(Hnl[o][il], W1[o * FFD + f], acc);
            float u = __builtin_amdgcn_exp2f(acc * -1.4426950408889634f);
            float hf = acc * __builtin_amdgcn_rcpf(1.0f + u);   // silu
#pragma unroll
            for (int o = 0; o < D_OUT; ++o)
                o2[o] = fmaf(hf, W2[f * D_OUT + o], o2[o]);
        }
#pragma unroll
        for (int o = 0; o < D_OUT; ++o) red2[o][tid] = o2[o];
    }
    __syncthreads();
    for (int idx = tid; idx < D_OUT * 16; idx += 256) {
        int d = idx >> 4, r = idx & 15;
        float s = b2[d];
#pragma unroll
        for (int g = 0; g < 16; ++g) s += red2[d][r + 16 * g];
        r2s[d][r] = s;
    }
    __syncthreads();
    {
        float kep = 0.f;
        float* op = out + (size_t)(row0 + il) * ZC;
        if (grp < 15) {
#pragma unroll
            for (int oo = 0; oo < 2; ++oo) {
                int o = o0 + oo;
                float acc = be[o];
#pragma unroll
                for (int d = 0; d < D_OUT; ++d)
                    acc = fmaf(r2s[d][il], We[d * D_OUT + o], acc);
                op[o] = acc;
                kep = fmaf(acc, acc, kep);
            }
        }
        ker[grp][il] = kep;
    }
    __syncthreads();
    if (tid < 16) {
        float ke = 0.f;
#pragma unroll
        for (int g = 0; g < 16; ++g) ke += ker[g][tid];
        float* op = out + (size_t)(row0 + tid) * ZC;
        op[30] = 0.f; op[31] = 0.f; op[32] = 0.f;
        op[33] = ke * (0.5f / D_OUT);
    }
}

// ---------------------------------------------------------------------------
extern "C" void kernel_launch(void* const* d_in, const int* in_sizes, int n_in,
                              void* d_out, int out_size, void* d_ws, size_t ws_size,
                              hipStream_t stream)
{
    const float* Z  = (const float*)d_in[1];
    const float* Wq = (const float*)d_in[2];
    const float* bq = (const float*)d_in[3];
    const float* Wk = (const float*)d_in[4];
    const float* bk = (const float*)d_in[5];
    const float* Wv = (const float*)d_in[6];
    const float* bv = (const float*)d_in[7];
    const float* Wo = (const float*)d_in[8];
    const float* bo = (const float*)d_in[9];
    const float* lg = (const float*)d_in[10];
    const float* lb = (const float*)d_in[11];
    const float* W1 = (const float*)d_in[12];
    const float* b1 = (const float*)d_in[13];
    const float* W2 = (const float*)d_in[14];
    const float* b2 = (const float*)d_in[15];
    const float* We = (const float*)d_in[16];
    const float* be = (const float*)d_in[17];
    float* out = (float*)d_out;

    ushort* Qb = (ushort*)d_ws;                 // N*32 bf16
    ushort* Kb = Qb + (size_t)N * HID;          // N*32 bf16
    ushort* Vt = Kb + (size_t)N * HID;          // [32][N] bf16
    float4* Pg = (float4*)(Vt + (size_t)N * HID);
    float* partial = (float*)(Pg + N);          // [JG][N][33] f32

    size_t base_bytes = (size_t)3 * N * HID * 2 + (size_t)N * 16;
    int JG = 16;
    while (JG > 1 && base_bytes + (size_t)JG * N * 33 * 4 > ws_size) JG >>= 1;
    int nch = N / (JG * 128);

    hipLaunchKernelGGL(dv_qkv_kernel, dim3((N * HID) / 256), dim3(256), 0, stream,
                       Z, Wq, bq, Wk, bk, Wv, bv, Qb, Kb, Vt, Pg);
    hipLaunchKernelGGL(dv_attn_kernel, dim3(64 * JG), dim3(256), 0, stream,
                       Qb, Kb, Vt, Pg, partial, nch);
    hipLaunchKernelGGL(dv_epilogue_kernel, dim3(N / 16), dim3(256), 0, stream,
                       partial, JG, Wo, bo, lg, lb, W1, b1, W2, b2, We, be, out);
}

// Round 5
// 77.319 us; speedup vs baseline: 1.0895x; 1.0895x over previous
//
#include <hip/hip_runtime.h>
#include <hip/hip_bf16.h>

#define N      8192
#define D_IN   30
#define HID    32
#define D_OUT  30
#define FFD    128
#define ZC     34

typedef __attribute__((ext_vector_type(8))) short short8;
typedef __attribute__((ext_vector_type(16))) float f32x16;
typedef __attribute__((ext_vector_type(2))) float f32x2;

static __device__ __forceinline__ ushort f2bf(float x) {
    uint32_t u = __float_as_uint(x);
    uint32_t r = (u + 0x7fffu + ((u >> 16) & 1u)) >> 16;   // RTNE
    return (ushort)r;
}

static __device__ __forceinline__ float rdlane(float v, int l) {
    return __uint_as_float(__builtin_amdgcn_readlane(__float_as_uint(v), l));
}

// ---------------------------------------------------------------------------
// Kernel A: QKV projections -> bf16, V transposed to Vt[32][N], and
// P' = (sqrt(2c)*p, -c*|p|^2) with c = log2e/(2*sigma^2). Q pre-scaled by
// log2e/sqrt(HID) so the QK MFMA output is directly the exp2 exponent.
// ---------------------------------------------------------------------------
__global__ __launch_bounds__(256) void dv_qkv_kernel(
    const float* __restrict__ Z,
    const float* __restrict__ Wq, const float* __restrict__ bq,
    const float* __restrict__ Wk, const float* __restrict__ bk,
    const float* __restrict__ Wv, const float* __restrict__ bv,
    ushort* __restrict__ Qb, ushort* __restrict__ Kb,
    ushort* __restrict__ Vt, float4* __restrict__ Pg)
{
    __shared__ ushort sv[8][33];
    const int t = blockIdx.x * 256 + threadIdx.x;
    const int i = t >> 5;
    const int h = t & 31;
    const float* z = Z + (size_t)i * ZC;

    float q = bq[h], k = bk[h], v = bv[h];
#pragma unroll
    for (int d = 0; d < D_IN; ++d) {
        float zf = z[d];
        q = fmaf(zf, Wq[d * HID + h], q);
        k = fmaf(zf, Wk[d * HID + h], k);
        v = fmaf(zf, Wv[d * HID + h], v);
    }
    const float QS = 0.17677669529663687f * 1.4426950408889634f; // log2e/sqrt(32)
    Qb[(size_t)i * HID + h] = f2bf(q * QS);
    Kb[(size_t)i * HID + h] = f2bf(k);
    sv[threadIdx.x >> 5][h] = f2bf(v);

    if (h == 0) {
        float p0 = z[D_IN], p1 = z[D_IN + 1], p2 = z[D_IN + 2];
        const float C2 = 1.4426950408889634f / 0.18f;   // log2e/(2*sigma^2)
        const float SC = sqrtf(2.0f * C2);
        float4 pp;
        pp.x = p0 * SC; pp.y = p1 * SC; pp.z = p2 * SC;
        pp.w = -C2 * (p0 * p0 + p1 * p1 + p2 * p2);
        Pg[i] = pp;
    }
    __syncthreads();
    const int ho = threadIdx.x >> 3, io = threadIdx.x & 7;
    const int i0 = blockIdx.x * 8;
    Vt[(size_t)ho * N + i0 + io] = sv[io][ho];
}

// ---------------------------------------------------------------------------
// Kernel B: fused MFMA attention (k-mapping-agnostic PV; see R3 notes).
// Grid = 64 row-blocks x JG. 4 waves/block, wave owns 32 i-rows.
// ---------------------------------------------------------------------------
__global__ __launch_bounds__(256, 2) void dv_attn_kernel(
    const ushort* __restrict__ Qb, const ushort* __restrict__ Kb,
    const ushort* __restrict__ Vt, const float4* __restrict__ Pg,
    float* __restrict__ partial, int nch)
{
    __shared__ ushort lK[128 * 32];   // K tile, 16B-chunk rot swizzle c'=(c+(j>>1))&3
    __shared__ ushort lV[32 * 128];   // V^T tile, 8B-chunk XOR swizzle c'=c^h
    __shared__ float lPx[128], lPy[128], lPz[128], lPw[128];

    const int tid  = threadIdx.x;
    const int lane = tid & 63;
    const int wv   = tid >> 6;
    const int h2   = lane >> 5;
    const int l31  = lane & 31;
    const int rb   = blockIdx.x & 63;
    const int jg   = blockIdx.x >> 6;
    const int i0w  = rb * 128 + wv * 32;

    const ushort* qp = Qb + (size_t)(i0w + l31) * HID + h2 * 8;
    const short8 qf0 = *(const short8*)qp;
    const short8 qf1 = *(const short8*)(qp + 16);
    const float4 psi = Pg[i0w + l31];
    const f32x2 psix = {psi.x, psi.x};
    const f32x2 psiy = {psi.y, psi.y};
    const f32x2 psiz = {psi.z, psi.z};
    const f32x2 psiw = {psi.w, psi.w};

    f32x16 zacc, oacc;
#pragma unroll
    for (int r = 0; r < 16; ++r) { zacc[r] = 0.f; oacc[r] = 0.f; }
    float ssA = 0.f, ssB = 0.f;

    const int cA0 = (h2 + (l31 >> 1)) & 3;
    const int cA1 = (cA0 + 2) & 3;

    for (int ch = 0; ch < nch; ++ch) {
        const int j0 = (jg * nch + ch) << 7;
        __syncthreads();
        {
            int idx = tid;
#pragma unroll
            for (int rep = 0; rep < 2; ++rep, idx += 256) {
                int jr = idx >> 2, c = idx & 3;
                int c2 = (c + (jr >> 1)) & 3;
                *(uint4*)&lK[jr * 32 + c2 * 8] =
                    *(const uint4*)&Kb[(size_t)(j0 + jr) * HID + c * 8];
            }
            idx = tid;
#pragma unroll
            for (int rep = 0; rep < 4; ++rep, idx += 256) {
                int hh = idx >> 5, cc = idx & 31;
                int cs = cc ^ hh;
                *(uint2*)&lV[hh * 128 + cs * 4] =
                    *(const uint2*)&Vt[(size_t)hh * N + j0 + cc * 4];
            }
            if (tid < 128) {
                float4 pp = Pg[j0 + tid];
                lPx[tid] = pp.x; lPy[tid] = pp.y;
                lPz[tid] = pp.z; lPw[tid] = pp.w;
            }
        }
        __syncthreads();

#pragma unroll
        for (int t32 = 0; t32 < 4; ++t32) {
            const ushort* krow = &lK[(t32 * 32 + l31) * 32];
            short8 kf0 = *(const short8*)&krow[cA0 * 8];
            short8 kf1 = *(const short8*)&krow[cA1 * 8];
            f32x16 s = __builtin_amdgcn_mfma_f32_32x32x16_bf16(kf0, qf0, zacc, 0, 0, 0);
            s = __builtin_amdgcn_mfma_f32_32x32x16_bf16(kf1, qf1, s, 0, 0, 0);

            const int pb = t32 * 32 + h2 * 4;
            uint32_t pk[8];
#pragma unroll
            for (int p = 0; p < 8; ++p) {
                const int jb = pb + ((2 * p) & 3) + 8 * (p >> 1);
                f32x2 px = *(const f32x2*)&lPx[jb];
                f32x2 py = *(const f32x2*)&lPy[jb];
                f32x2 pz = *(const f32x2*)&lPz[jb];
                f32x2 pw = *(const f32x2*)&lPw[jb];
                f32x2 tt = __builtin_elementwise_fma(px, psix, pw);
                tt = __builtin_elementwise_fma(py, psiy, tt);
                tt = __builtin_elementwise_fma(pz, psiz, tt);
                tt = tt + psiw;                         // = -D (<= 0 + eps)
                f32x2 sp = {s[2 * p], s[2 * p + 1]};
                f32x2 ts = tt + sp;                     // = S' - D
                float e0a = __builtin_amdgcn_exp2f(-tt[0]);   // 2^D
                float e0b = __builtin_amdgcn_exp2f(-ts[0]);   // 2^(D-S')
                float a0  = __builtin_amdgcn_rcpf(e0a + e0b);
                float e1a = __builtin_amdgcn_exp2f(-tt[1]);
                float e1b = __builtin_amdgcn_exp2f(-ts[1]);
                float a1  = __builtin_amdgcn_rcpf(e1a + e1b);
                ssA += a0;
                ssB += a1;
                asm("v_cvt_pk_bf16_f32 %0, %1, %2" : "=v"(pk[p]) : "v"(a0), "v"(a1));
            }
            union BV { uint32_t u[4]; short8 v; };
            BV fa, fb;
            fa.u[0] = pk[0]; fa.u[1] = pk[1]; fa.u[2] = pk[2]; fa.u[3] = pk[3];
            fb.u[0] = pk[4]; fb.u[1] = pk[5]; fb.u[2] = pk[6]; fb.u[3] = pk[7];

            const ushort* vrow = &lV[l31 * 128];
            const int cb = t32 * 8 + h2;
            BV b0, b1;
            *(uint2*)&b0.u[0] = *(const uint2*)&vrow[((cb    ) ^ l31) * 4];
            *(uint2*)&b0.u[2] = *(const uint2*)&vrow[((cb + 2) ^ l31) * 4];
            *(uint2*)&b1.u[0] = *(const uint2*)&vrow[((cb + 4) ^ l31) * 4];
            *(uint2*)&b1.u[2] = *(const uint2*)&vrow[((cb + 6) ^ l31) * 4];

            oacc = __builtin_amdgcn_mfma_f32_32x32x16_bf16(fa.v, b0.v, oacc, 0, 0, 0);
            oacc = __builtin_amdgcn_mfma_f32_32x32x16_bf16(fb.v, b1.v, oacc, 0, 0, 0);
        }
    }

    float ssum = ssA + ssB;
    float sst = ssum + __shfl_xor(ssum, 32, 64);
    const size_t pbase = (size_t)jg * N * 33;
    if (lane < 32)
        partial[pbase + (size_t)(i0w + lane) * 33 + 32] = sst;
#pragma unroll
    for (int r = 0; r < 16; ++r) {
        int ir = (r & 3) + 8 * (r >> 2) + 4 * h2 + i0w;
        partial[pbase + (size_t)ir * 33 + l31] = oacc[r];
    }
}

// ---------------------------------------------------------------------------
// Kernel C: wave-per-row epilogue, barrier-free, zero LDS.
// Wave owns row i: fused JG-reduce (coalesced 33-float row reads), then
// Wo GEMV / LayerNorm / FFN / We with all cross-lane traffic via v_readlane
// (uniform compile-time index) and __shfl_xor butterflies. Grid 2048x256.
// ---------------------------------------------------------------------------
__global__ __launch_bounds__(256) void dv_epilogue_kernel(
    const float* __restrict__ partial, int JG,
    const float* __restrict__ Wo, const float* __restrict__ bo,
    const float* __restrict__ ln_g, const float* __restrict__ ln_b,
    const float* __restrict__ W1, const float* __restrict__ b1,
    const float* __restrict__ W2, const float* __restrict__ b2,
    const float* __restrict__ We, const float* __restrict__ be,
    float* __restrict__ out)
{
    const int tid  = threadIdx.x;
    const int lane = tid & 63;
    const int row  = blockIdx.x * 4 + (tid >> 6);
    const bool a30 = lane < 30;
    const int  o30 = a30 ? lane : 0;

    // Fused reduce over JG partials: lane c holds red[c], c < 33.
    float rv = 0.f;
    if (lane < 33) {
        const float* pp = partial + (size_t)row * 33 + lane;
#pragma unroll 4
        for (int jg = 0; jg < JG; ++jg)
            rv += pp[(size_t)jg * N * 33];
    }

    const float inv = __builtin_amdgcn_rcpf(rdlane(rv, 32) + 1e-8f);

    // H[o] = bo[o] + sum_h (red[h]*inv) * Wo[h][o]   (lane o)
    float H = a30 ? bo[lane] : 0.f;
#pragma unroll
    for (int h = 0; h < HID; ++h) {
        float ah = rdlane(rv, h) * inv;
        H = fmaf(ah, Wo[h * D_OUT + o30], H);
    }
    float Hm = a30 ? H : 0.f;

    // LayerNorm across lanes 0..29
    float t = Hm;
#pragma unroll
    for (int m = 1; m < 64; m <<= 1) t += __shfl_xor(t, m, 64);
    float mu = t * (1.0f / D_OUT);
    float d  = a30 ? (H - mu) : 0.f;
    float v2 = d * d;
#pragma unroll
    for (int m = 1; m < 64; m <<= 1) v2 += __shfl_xor(v2, m, 64);
    float rs = rsqrtf(v2 * (1.0f / D_OUT) + 1e-5f);
    float Hn = fmaf(d * rs, ln_g[o30], ln_b[o30]);   // valid for lane<30

    // FFN layer 1 + SiLU: lane owns f = lane and f = lane+64
    float a0 = b1[lane], a1 = b1[lane + 64];
#pragma unroll
    for (int o = 0; o < D_OUT; ++o) {
        float ho = rdlane(Hn, o);
        a0 = fmaf(ho, W1[o * FFD + lane], a0);
        a1 = fmaf(ho, W1[o * FFD + lane + 64], a1);
    }
    const float L2E = 1.4426950408889634f;
    float hf0 = a0 * __builtin_amdgcn_rcpf(1.0f + __builtin_amdgcn_exp2f(-a0 * L2E));
    float hf1 = a1 * __builtin_amdgcn_rcpf(1.0f + __builtin_amdgcn_exp2f(-a1 * L2E));

    // FFN layer 2: lane d accumulates H2[d]
    float H2 = a30 ? b2[lane] : 0.f;
#pragma unroll
    for (int f = 0; f < 64; ++f) {
        H2 = fmaf(rdlane(hf0, f), W2[f * D_OUT + o30], H2);
        H2 = fmaf(rdlane(hf1, f), W2[(f + 64) * D_OUT + o30], H2);
    }

    // We GEMV: lane o computes output feature o
    float acc = a30 ? be[lane] : 0.f;
#pragma unroll
    for (int dd = 0; dd < D_OUT; ++dd)
        acc = fmaf(rdlane(H2, dd), We[dd * D_OUT + o30], acc);

    float kep = a30 ? acc * acc : 0.f;
#pragma unroll
    for (int m = 1; m < 64; m <<= 1) kep += __shfl_xor(kep, m, 64);

    if (lane < ZC) {
        float outv;
        if (a30)            outv = acc;
        else if (lane < 33) outv = 0.f;
        else                outv = kep * (0.5f / D_OUT);
        out[(size_t)row * ZC + lane] = outv;
    }
}

// ---------------------------------------------------------------------------
extern "C" void kernel_launch(void* const* d_in, const int* in_sizes, int n_in,
                              void* d_out, int out_size, void* d_ws, size_t ws_size,
                              hipStream_t stream)
{
    const float* Z  = (const float*)d_in[1];
    const float* Wq = (const float*)d_in[2];
    const float* bq = (const float*)d_in[3];
    const float* Wk = (const float*)d_in[4];
    const float* bk = (const float*)d_in[5];
    const float* Wv = (const float*)d_in[6];
    const float* bv = (const float*)d_in[7];
    const float* Wo = (const float*)d_in[8];
    const float* bo = (const float*)d_in[9];
    const float* lg = (const float*)d_in[10];
    const float* lb = (const float*)d_in[11];
    const float* W1 = (const float*)d_in[12];
    const float* b1 = (const float*)d_in[13];
    const float* W2 = (const float*)d_in[14];
    const float* b2 = (const float*)d_in[15];
    const float* We = (const float*)d_in[16];
    const float* be = (const float*)d_in[17];
    float* out = (float*)d_out;

    ushort* Qb = (ushort*)d_ws;                 // N*32 bf16
    ushort* Kb = Qb + (size_t)N * HID;          // N*32 bf16
    ushort* Vt = Kb + (size_t)N * HID;          // [32][N] bf16
    float4* Pg = (float4*)(Vt + (size_t)N * HID);
    float* partial = (float*)(Pg + N);          // [JG][N][33] f32

    size_t base_bytes = (size_t)3 * N * HID * 2 + (size_t)N * 16;
    int JG = 16;
    while (JG > 1 && base_bytes + (size_t)JG * N * 33 * 4 > ws_size) JG >>= 1;
    int nch = N / (JG * 128);

    hipLaunchKernelGGL(dv_qkv_kernel, dim3((N * HID) / 256), dim3(256), 0, stream,
                       Z, Wq, bq, Wk, bk, Wv, bv, Qb, Kb, Vt, Pg);
    hipLaunchKernelGGL(dv_attn_kernel, dim3(64 * JG), dim3(256), 0, stream,
                       Qb, Kb, Vt, Pg, partial, nch);
    hipLaunchKernelGGL(dv_epilogue_kernel, dim3(N / 4), dim3(256), 0, stream,
                       partial, JG, Wo, bo, lg, lb, W1, b1, W2, b2, We, be, out);
}

// Round 6
// 69.494 us; speedup vs baseline: 1.2121x; 1.1126x over previous
//
#include <hip/hip_runtime.h>
#include <hip/hip_bf16.h>

#define N      8192
#define D_IN   30
#define HID    32
#define D_OUT  30
#define FFD    128
#define ZC     34

typedef __attribute__((ext_vector_type(8))) short short8;
typedef __attribute__((ext_vector_type(16))) float f32x16;
typedef __attribute__((ext_vector_type(2))) float f32x2;

static __device__ __forceinline__ ushort f2bf(float x) {
    uint32_t u = __float_as_uint(x);
    uint32_t r = (u + 0x7fffu + ((u >> 16) & 1u)) >> 16;   // RTNE
    return (ushort)r;
}

// ---------------------------------------------------------------------------
// Kernel A: QKV projections -> bf16, V transposed to Vt[32][N], and
// P' = (sqrt(2c)*p, -c*|p|^2) with c = log2e/(2*sigma^2). Q pre-scaled by
// log2e/sqrt(HID) so the QK MFMA output is directly the exp2 exponent.
// ---------------------------------------------------------------------------
__global__ __launch_bounds__(256) void dv_qkv_kernel(
    const float* __restrict__ Z,
    const float* __restrict__ Wq, const float* __restrict__ bq,
    const float* __restrict__ Wk, const float* __restrict__ bk,
    const float* __restrict__ Wv, const float* __restrict__ bv,
    ushort* __restrict__ Qb, ushort* __restrict__ Kb,
    ushort* __restrict__ Vt, float4* __restrict__ Pg)
{
    __shared__ ushort sv[8][33];
    const int t = blockIdx.x * 256 + threadIdx.x;
    const int i = t >> 5;
    const int h = t & 31;
    const float* z = Z + (size_t)i * ZC;

    float q = bq[h], k = bk[h], v = bv[h];
#pragma unroll
    for (int d = 0; d < D_IN; ++d) {
        float zf = z[d];
        q = fmaf(zf, Wq[d * HID + h], q);
        k = fmaf(zf, Wk[d * HID + h], k);
        v = fmaf(zf, Wv[d * HID + h], v);
    }
    const float QS = 0.17677669529663687f * 1.4426950408889634f; // log2e/sqrt(32)
    Qb[(size_t)i * HID + h] = f2bf(q * QS);
    Kb[(size_t)i * HID + h] = f2bf(k);
    sv[threadIdx.x >> 5][h] = f2bf(v);

    if (h == 0) {
        float p0 = z[D_IN], p1 = z[D_IN + 1], p2 = z[D_IN + 2];
        const float C2 = 1.4426950408889634f / 0.18f;   // log2e/(2*sigma^2)
        const float SC = sqrtf(2.0f * C2);
        float4 pp;
        pp.x = p0 * SC; pp.y = p1 * SC; pp.z = p2 * SC;
        pp.w = -C2 * (p0 * p0 + p1 * p1 + p2 * p2);
        Pg[i] = pp;
    }
    __syncthreads();
    const int ho = threadIdx.x >> 3, io = threadIdx.x & 7;
    const int i0 = blockIdx.x * 8;
    Vt[(size_t)ho * N + i0 + io] = sv[io][ho];
}

// ---------------------------------------------------------------------------
// Kernel B: fused MFMA attention (k-mapping-agnostic PV; see R3 notes).
// Grid = 64 row-blocks x JG. 4 waves/block, wave owns 32 i-rows.
// ---------------------------------------------------------------------------
__global__ __launch_bounds__(256, 2) void dv_attn_kernel(
    const ushort* __restrict__ Qb, const ushort* __restrict__ Kb,
    const ushort* __restrict__ Vt, const float4* __restrict__ Pg,
    float* __restrict__ partial, int nch)
{
    __shared__ ushort lK[128 * 32];   // K tile, 16B-chunk rot swizzle c'=(c+(j>>1))&3
    __shared__ ushort lV[32 * 128];   // V^T tile, 8B-chunk XOR swizzle c'=c^h
    __shared__ float lPx[128], lPy[128], lPz[128], lPw[128];

    const int tid  = threadIdx.x;
    const int lane = tid & 63;
    const int wv   = tid >> 6;
    const int h2   = lane >> 5;
    const int l31  = lane & 31;
    const int rb   = blockIdx.x & 63;
    const int jg   = blockIdx.x >> 6;
    const int i0w  = rb * 128 + wv * 32;

    const ushort* qp = Qb + (size_t)(i0w + l31) * HID + h2 * 8;
    const short8 qf0 = *(const short8*)qp;
    const short8 qf1 = *(const short8*)(qp + 16);
    const float4 psi = Pg[i0w + l31];
    const f32x2 psix = {psi.x, psi.x};
    const f32x2 psiy = {psi.y, psi.y};
    const f32x2 psiz = {psi.z, psi.z};
    const f32x2 psiw = {psi.w, psi.w};

    f32x16 zacc, oacc;
#pragma unroll
    for (int r = 0; r < 16; ++r) { zacc[r] = 0.f; oacc[r] = 0.f; }
    float ssA = 0.f, ssB = 0.f;

    const int cA0 = (h2 + (l31 >> 1)) & 3;
    const int cA1 = (cA0 + 2) & 3;

    for (int ch = 0; ch < nch; ++ch) {
        const int j0 = (jg * nch + ch) << 7;
        __syncthreads();
        {
            int idx = tid;
#pragma unroll
            for (int rep = 0; rep < 2; ++rep, idx += 256) {
                int jr = idx >> 2, c = idx & 3;
                int c2 = (c + (jr >> 1)) & 3;
                *(uint4*)&lK[jr * 32 + c2 * 8] =
                    *(const uint4*)&Kb[(size_t)(j0 + jr) * HID + c * 8];
            }
            idx = tid;
#pragma unroll
            for (int rep = 0; rep < 4; ++rep, idx += 256) {
                int hh = idx >> 5, cc = idx & 31;
                int cs = cc ^ hh;
                *(uint2*)&lV[hh * 128 + cs * 4] =
                    *(const uint2*)&Vt[(size_t)hh * N + j0 + cc * 4];
            }
            if (tid < 128) {
                float4 pp = Pg[j0 + tid];
                lPx[tid] = pp.x; lPy[tid] = pp.y;
                lPz[tid] = pp.z; lPw[tid] = pp.w;
            }
        }
        __syncthreads();

#pragma unroll
        for (int t32 = 0; t32 < 4; ++t32) {
            const ushort* krow = &lK[(t32 * 32 + l31) * 32];
            short8 kf0 = *(const short8*)&krow[cA0 * 8];
            short8 kf1 = *(const short8*)&krow[cA1 * 8];
            f32x16 s = __builtin_amdgcn_mfma_f32_32x32x16_bf16(kf0, qf0, zacc, 0, 0, 0);
            s = __builtin_amdgcn_mfma_f32_32x32x16_bf16(kf1, qf1, s, 0, 0, 0);

            const int pb = t32 * 32 + h2 * 4;
            uint32_t pk[8];
#pragma unroll
            for (int p = 0; p < 8; ++p) {
                const int jb = pb + ((2 * p) & 3) + 8 * (p >> 1);
                f32x2 px = *(const f32x2*)&lPx[jb];
                f32x2 py = *(const f32x2*)&lPy[jb];
                f32x2 pz = *(const f32x2*)&lPz[jb];
                f32x2 pw = *(const f32x2*)&lPw[jb];
                f32x2 tt = __builtin_elementwise_fma(px, psix, pw);
                tt = __builtin_elementwise_fma(py, psiy, tt);
                tt = __builtin_elementwise_fma(pz, psiz, tt);
                tt = tt + psiw;                         // = -D (<= 0 + eps)
                f32x2 sp = {s[2 * p], s[2 * p + 1]};
                f32x2 ts = tt + sp;                     // = S' - D
                float e0a = __builtin_amdgcn_exp2f(-tt[0]);   // 2^D
                float e0b = __builtin_amdgcn_exp2f(-ts[0]);   // 2^(D-S')
                float a0  = __builtin_amdgcn_rcpf(e0a + e0b);
                float e1a = __builtin_amdgcn_exp2f(-tt[1]);
                float e1b = __builtin_amdgcn_exp2f(-ts[1]);
                float a1  = __builtin_amdgcn_rcpf(e1a + e1b);
                ssA += a0;
                ssB += a1;
                asm("v_cvt_pk_bf16_f32 %0, %1, %2" : "=v"(pk[p]) : "v"(a0), "v"(a1));
            }
            union BV { uint32_t u[4]; short8 v; };
            BV fa, fb;
            fa.u[0] = pk[0]; fa.u[1] = pk[1]; fa.u[2] = pk[2]; fa.u[3] = pk[3];
            fb.u[0] = pk[4]; fb.u[1] = pk[5]; fb.u[2] = pk[6]; fb.u[3] = pk[7];

            const ushort* vrow = &lV[l31 * 128];
            const int cb = t32 * 8 + h2;
            BV b0, b1;
            *(uint2*)&b0.u[0] = *(const uint2*)&vrow[((cb    ) ^ l31) * 4];
            *(uint2*)&b0.u[2] = *(const uint2*)&vrow[((cb + 2) ^ l31) * 4];
            *(uint2*)&b1.u[0] = *(const uint2*)&vrow[((cb + 4) ^ l31) * 4];
            *(uint2*)&b1.u[2] = *(const uint2*)&vrow[((cb + 6) ^ l31) * 4];

            oacc = __builtin_amdgcn_mfma_f32_32x32x16_bf16(fa.v, b0.v, oacc, 0, 0, 0);
            oacc = __builtin_amdgcn_mfma_f32_32x32x16_bf16(fb.v, b1.v, oacc, 0, 0, 0);
        }
    }

    float ssum = ssA + ssB;
    float sst = ssum + __shfl_xor(ssum, 32, 64);
    const size_t pbase = (size_t)jg * N * 33;
    if (lane < 32)
        partial[pbase + (size_t)(i0w + lane) * 33 + 32] = sst;
#pragma unroll
    for (int r = 0; r < 16; ++r) {
        int ir = (r & 3) + 8 * (r >> 2) + 4 * h2 + i0w;
        partial[pbase + (size_t)ir * 33 + l31] = oacc[r];
    }
}

// ---------------------------------------------------------------------------
// Kernel C: fused JG-reduce + epilogue, register-blocked.
// 256 blocks x 256 thr; block = 32 rows. Thread = (rl = tid&15 -> rows
// 2rl,2rl+1) x (grp = tid>>4 -> 2 outputs / 8 FF dims). Each weight load
// feeds 4 fma. W2 and intermediates staged in LDS with stride-34 padding
// so row-pairs read as aligned b64.
// ---------------------------------------------------------------------------
__global__ __launch_bounds__(256) void dv_epilogue_kernel(
    const float* __restrict__ partial, int JG,
    const float* __restrict__ Wo, const float* __restrict__ bo,
    const float* __restrict__ ln_g, const float* __restrict__ ln_b,
    const float* __restrict__ W1, const float* __restrict__ b1,
    const float* __restrict__ W2, const float* __restrict__ b2,
    const float* __restrict__ We, const float* __restrict__ be,
    float* __restrict__ out)
{
    __shared__ float sr [33 * 34];    // [c][r] stride 34 (b64-aligned row pairs)
    __shared__ float sHl[30 * 33];    // [o][r] stride 33 (scalar access)
    __shared__ float sHn[30 * 34];    // [o][r] stride 34
    __shared__ float shf[128 * 34];   // [f][r] stride 34
    __shared__ float sW2[FFD * D_OUT];// raw W2 copy [f][o]
    __shared__ float sH2[30 * 34];    // [d][r] stride 34
    __shared__ float sker[15 * 33];   // [grp][r] stride 33

    const int tid  = threadIdx.x;
    const int row0 = blockIdx.x * 32;

    // stage W2 into LDS (coalesced, same layout)
    for (int idx = tid; idx < FFD * D_OUT; idx += 256)
        sW2[idx] = W2[idx];

    // fused JG-reduction: sr[c][r] = sum_jg partial[jg][row0+r][c]
    for (int idx = tid; idx < 33 * 32; idx += 256) {
        int r = idx / 33, c = idx - r * 33;
        const float* pp = partial + (size_t)(row0 + r) * 33 + c;
        float s = 0.f;
#pragma unroll 4
        for (int jg = 0; jg < JG; ++jg)
            s += pp[(size_t)jg * N * 33];
        sr[c * 34 + r] = s;
    }
    __syncthreads();                                    // B1

    const int rl  = tid & 15, grp = tid >> 4;
    const int r0  = rl * 2, r1 = r0 + 1;
    const int o0  = grp * 2;
    const bool g15 = grp < 15;

    // Phase 2: Wo GEMV (raw, normalize at the end)
    if (g15) {
        float a00 = 0.f, a01 = 0.f, a10 = 0.f, a11 = 0.f;
#pragma unroll
        for (int h = 0; h < HID; ++h) {
            float2 w = *(const float2*)&Wo[h * D_OUT + o0];
            float2 s2 = *(const float2*)&sr[h * 34 + r0];
            a00 = fmaf(s2.x, w.x, a00); a01 = fmaf(s2.x, w.y, a01);
            a10 = fmaf(s2.y, w.x, a10); a11 = fmaf(s2.y, w.y, a11);
        }
        float2 sv = *(const float2*)&sr[32 * 34 + r0];
        float inv0 = __builtin_amdgcn_rcpf(sv.x + 1e-8f);
        float inv1 = __builtin_amdgcn_rcpf(sv.y + 1e-8f);
        float2 bb = *(const float2*)&bo[o0];
        sHl[(o0    ) * 33 + r0] = fmaf(a00, inv0, bb.x);
        sHl[(o0 + 1) * 33 + r0] = fmaf(a01, inv0, bb.y);
        sHl[(o0    ) * 33 + r1] = fmaf(a10, inv1, bb.x);
        sHl[(o0 + 1) * 33 + r1] = fmaf(a11, inv1, bb.y);
    }
    __syncthreads();                                    // B2

    // Phase 3: LayerNorm per row (threads 0..31)
    if (tid < 32) {
        const int r = tid;
        float mu = 0.f;
#pragma unroll
        for (int o = 0; o < D_OUT; ++o) mu += sHl[o * 33 + r];
        mu *= (1.0f / D_OUT);
        float var = 0.f;
#pragma unroll
        for (int o = 0; o < D_OUT; ++o) {
            float d = sHl[o * 33 + r] - mu; var = fmaf(d, d, var);
        }
        float rs = rsqrtf(var * (1.0f / D_OUT) + 1e-5f);
#pragma unroll
        for (int o = 0; o < D_OUT; ++o)
            sHn[o * 34 + r] = fmaf((sHl[o * 33 + r] - mu) * rs, ln_g[o], ln_b[o]);
    }
    __syncthreads();                                    // B3

    // Phase 4: FFN1 + SiLU (all 16 grps: 8 FF dims each, 2 rows)
    {
        const int f0 = grp * 8;
        float accA[8], accB[8];
        float4 b4a = *(const float4*)&b1[f0];
        float4 b4b = *(const float4*)&b1[f0 + 4];
        accA[0] = b4a.x; accA[1] = b4a.y; accA[2] = b4a.z; accA[3] = b4a.w;
        accA[4] = b4b.x; accA[5] = b4b.y; accA[6] = b4b.z; accA[7] = b4b.w;
#pragma unroll
        for (int ff = 0; ff < 8; ++ff) accB[ff] = accA[ff];
#pragma unroll
        for (int o = 0; o < D_OUT; ++o) {
            float4 wa = *(const float4*)&W1[o * FFD + f0];
            float4 wb = *(const float4*)&W1[o * FFD + f0 + 4];
            float2 h2 = *(const float2*)&sHn[o * 34 + r0];
            float wv[8] = {wa.x, wa.y, wa.z, wa.w, wb.x, wb.y, wb.z, wb.w};
#pragma unroll
            for (int ff = 0; ff < 8; ++ff) {
                accA[ff] = fmaf(h2.x, wv[ff], accA[ff]);
                accB[ff] = fmaf(h2.y, wv[ff], accB[ff]);
            }
        }
        const float L2E = 1.4426950408889634f;
#pragma unroll
        for (int ff = 0; ff < 8; ++ff) {
            float a = accA[ff];
            shf[(f0 + ff) * 34 + r0] =
                a * __builtin_amdgcn_rcpf(1.0f + __builtin_amdgcn_exp2f(-a * L2E));
            a = accB[ff];
            shf[(f0 + ff) * 34 + r1] =
                a * __builtin_amdgcn_rcpf(1.0f + __builtin_amdgcn_exp2f(-a * L2E));
        }
    }
    __syncthreads();                                    // B4

    // Phase 5: FFN2 (H2 = hf @ W2 + b2), b64-paired LDS reads
    if (g15) {
        float2 bb = *(const float2*)&b2[o0];
        float a00 = bb.x, a01 = bb.y, a10 = bb.x, a11 = bb.y;
#pragma unroll 4
        for (int f = 0; f < FFD; ++f) {
            float2 w  = *(const float2*)&sW2[f * D_OUT + o0];
            float2 h2 = *(const float2*)&shf[f * 34 + r0];
            a00 = fmaf(h2.x, w.x, a00); a01 = fmaf(h2.x, w.y, a01);
            a10 = fmaf(h2.y, w.x, a10); a11 = fmaf(h2.y, w.y, a11);
        }
        sH2[(o0    ) * 34 + r0] = a00;
        sH2[(o0 + 1) * 34 + r0] = a01;
        sH2[(o0    ) * 34 + r1] = a10;
        sH2[(o0 + 1) * 34 + r1] = a11;
    }
    __syncthreads();                                    // B5

    // Phase 6: We GEMV + ke partials + main output stores
    if (g15) {
        float2 bb = *(const float2*)&be[o0];
        float a00 = bb.x, a01 = bb.y, a10 = bb.x, a11 = bb.y;
#pragma unroll
        for (int d = 0; d < D_OUT; ++d) {
            float2 w  = *(const float2*)&We[d * D_OUT + o0];
            float2 h2 = *(const float2*)&sH2[d * 34 + r0];
            a00 = fmaf(h2.x, w.x, a00); a01 = fmaf(h2.x, w.y, a01);
            a10 = fmaf(h2.y, w.x, a10); a11 = fmaf(h2.y, w.y, a11);
        }
        float* op0 = out + (size_t)(row0 + r0) * ZC;
        float* op1 = out + (size_t)(row0 + r1) * ZC;
        op0[o0] = a00; op0[o0 + 1] = a01;
        op1[o0] = a10; op1[o0 + 1] = a11;
        sker[grp * 33 + r0] = fmaf(a00, a00, a01 * a01);
        sker[grp * 33 + r1] = fmaf(a10, a10, a11 * a11);
    }
    __syncthreads();                                    // B6

    if (tid < 32) {
        const int r = tid;
        float ke = 0.f;
#pragma unroll
        for (int g = 0; g < 15; ++g) ke += sker[g * 33 + r];
        float* op = out + (size_t)(row0 + r) * ZC;
        op[30] = 0.f; op[31] = 0.f; op[32] = 0.f;
        op[33] = ke * (0.5f / D_OUT);
    }
}

// ---------------------------------------------------------------------------
extern "C" void kernel_launch(void* const* d_in, const int* in_sizes, int n_in,
                              void* d_out, int out_size, void* d_ws, size_t ws_size,
                              hipStream_t stream)
{
    const float* Z  = (const float*)d_in[1];
    const float* Wq = (const float*)d_in[2];
    const float* bq = (const float*)d_in[3];
    const float* Wk = (const float*)d_in[4];
    const float* bk = (const float*)d_in[5];
    const float* Wv = (const float*)d_in[6];
    const float* bv = (const float*)d_in[7];
    const float* Wo = (const float*)d_in[8];
    const float* bo = (const float*)d_in[9];
    const float* lg = (const float*)d_in[10];
    const float* lb = (const float*)d_in[11];
    const float* W1 = (const float*)d_in[12];
    const float* b1 = (const float*)d_in[13];
    const float* W2 = (const float*)d_in[14];
    const float* b2 = (const float*)d_in[15];
    const float* We = (const float*)d_in[16];
    const float* be = (const float*)d_in[17];
    float* out = (float*)d_out;

    ushort* Qb = (ushort*)d_ws;                 // N*32 bf16
    ushort* Kb = Qb + (size_t)N * HID;          // N*32 bf16
    ushort* Vt = Kb + (size_t)N * HID;          // [32][N] bf16
    float4* Pg = (float4*)(Vt + (size_t)N * HID);
    float* partial = (float*)(Pg + N);          // [JG][N][33] f32

    size_t base_bytes = (size_t)3 * N * HID * 2 + (size_t)N * 16;
    int JG = 16;
    while (JG > 1 && base_bytes + (size_t)JG * N * 33 * 4 > ws_size) JG >>= 1;
    int nch = N / (JG * 128);

    hipLaunchKernelGGL(dv_qkv_kernel, dim3((N * HID) / 256), dim3(256), 0, stream,
                       Z, Wq, bq, Wk, bk, Wv, bv, Qb, Kb, Vt, Pg);
    hipLaunchKernelGGL(dv_attn_kernel, dim3(64 * JG), dim3(256), 0, stream,
                       Qb, Kb, Vt, Pg, partial, nch);
    hipLaunchKernelGGL(dv_epilogue_kernel, dim3(N / 32), dim3(256), 0, stream,
                       partial, JG, Wo, bo, lg, lb, W1, b1, W2, b2, We, be, out);
}

// Round 8
// 66.847 us; speedup vs baseline: 1.2601x; 1.0396x over previous
//
#include <hip/hip_runtime.h>
#include <hip/hip_bf16.h>

#define N      8192
#define D_IN   30
#define HID    32
#define D_OUT  30
#define FFD    128
#define ZC     34

typedef __attribute__((ext_vector_type(8))) short short8;
typedef __attribute__((ext_vector_type(16))) float f32x16;
typedef __attribute__((ext_vector_type(2))) float f32x2;

static __device__ __forceinline__ ushort f2bf(float x) {
    uint32_t u = __float_as_uint(x);
    uint32_t r = (u + 0x7fffu + ((u >> 16) & 1u)) >> 16;   // RTNE
    return (ushort)r;
}
static __device__ __forceinline__ float bf2f(ushort u) {
    return __uint_as_float(((uint32_t)u) << 16);
}

// ---------------------------------------------------------------------------
// Kernel A: QKV projections -> bf16 (Q pre-scaled by log2e/sqrt(HID)),
// V transposed to Vt[32][N], split-precision gate-augmentation tables
// (KA = MFMA A-side per j, QB = MFMA B-side per i, each [2 halves][N][8]),
// and W2e = W2 @ We (+ b2e = b2 @ We + be) fused-epilogue weights.
// Gate identity: -D = wj + wi + p'_j . p'_i  with p' = sqrt(2c) p,
// w = -c|p|^2, c = log2e/(2 sigma^2); hi/lo bf16 split keeps ~16-bit prec.
// ---------------------------------------------------------------------------
__global__ __launch_bounds__(256) void dv_qkv_kernel(
    const float* __restrict__ Z,
    const float* __restrict__ Wq, const float* __restrict__ bq,
    const float* __restrict__ Wk, const float* __restrict__ bk,
    const float* __restrict__ Wv, const float* __restrict__ bv,
    const float* __restrict__ W2, const float* __restrict__ We,
    const float* __restrict__ b2, const float* __restrict__ be,
    ushort* __restrict__ Qb, ushort* __restrict__ Kb,
    ushort* __restrict__ Vt, ushort* __restrict__ KA,
    ushort* __restrict__ QB, float* __restrict__ W2e, float* __restrict__ b2e)
{
    __shared__ ushort sv[8][33];
    const int t = blockIdx.x * 256 + threadIdx.x;
    const int i = t >> 5;
    const int h = t & 31;
    const float* z = Z + (size_t)i * ZC;

    float q = bq[h], k = bk[h], v = bv[h];
#pragma unroll
    for (int d = 0; d < D_IN; ++d) {
        float zf = z[d];
        q = fmaf(zf, Wq[d * HID + h], q);
        k = fmaf(zf, Wk[d * HID + h], k);
        v = fmaf(zf, Wv[d * HID + h], v);
    }
    const float QS = 0.17677669529663687f * 1.4426950408889634f; // log2e/sqrt(32)
    Qb[(size_t)i * HID + h] = f2bf(q * QS);
    Kb[(size_t)i * HID + h] = f2bf(k);
    sv[threadIdx.x >> 5][h] = f2bf(v);

    if (h == 0) {
        float p0 = z[D_IN], p1 = z[D_IN + 1], p2 = z[D_IN + 2];
        const float C2 = 1.4426950408889634f / 0.18f;   // log2e/(2*sigma^2)
        const float SC = sqrtf(2.0f * C2);
        float px = p0 * SC, py = p1 * SC, pz = p2 * SC;
        float w  = -C2 * (p0 * p0 + p1 * p1 + p2 * p2);
        ushort phx = f2bf(px), phy = f2bf(py), phz = f2bf(pz);
        ushort plx = f2bf(px - bf2f(phx));
        ushort ply = f2bf(py - bf2f(phy));
        ushort plz = f2bf(pz - bf2f(phz));
        ushort wh  = f2bf(w);
        ushort wl  = f2bf(w - bf2f(wh));
        const ushort one = 0x3F80;
        ushort ka0[8] = {wh, wl, one, one, phx, phy, phz, phx};
        ushort ka1[8] = {phy, phz, plx, ply, plz, plx, ply, plz};
        ushort qb0[8] = {one, one, wh, wl, phx, phy, phz, plx};
        ushort qb1[8] = {ply, plz, phx, phy, phz, plx, ply, plz};
        *(uint4*)&KA[(size_t)i * 8]           = *(uint4*)ka0;
        *(uint4*)&KA[((size_t)N + i) * 8]     = *(uint4*)ka1;
        *(uint4*)&QB[(size_t)i * 8]           = *(uint4*)qb0;
        *(uint4*)&QB[((size_t)N + i) * 8]     = *(uint4*)qb1;
    }

    // W2e = W2 @ We  (3840 elements over the first 15 blocks)
    if (blockIdx.x < 15) {
        int idx = blockIdx.x * 256 + threadIdx.x;      // 0..3839
        int f = idx / 30, o = idx - f * 30;
        float acc = 0.f;
#pragma unroll
        for (int d = 0; d < D_OUT; ++d)
            acc = fmaf(W2[f * D_OUT + d], We[d * D_OUT + o], acc);
        W2e[idx] = acc;
        if (idx < D_OUT) {
            float a2 = be[idx];
#pragma unroll
            for (int d = 0; d < D_OUT; ++d)
                a2 = fmaf(b2[d], We[d * D_OUT + idx], a2);
            b2e[idx] = a2;
        }
    }

    __syncthreads();
    const int ho = threadIdx.x >> 3, io = threadIdx.x & 7;
    const int i0 = blockIdx.x * 8;
    Vt[(size_t)ho * N + i0 + io] = sv[io][ho];
}

// ---------------------------------------------------------------------------
// Kernel B: fused MFMA attention. Per 32x32 tile: 2 MFMA for S' (swapped
// K,Q operands -> lane=i, acc rows=j), 1 MFMA for the gate exponent
// G = -D (augmented split-bf16 operands, clamped <= 0), then the INF-FREE
// gate a = 2^G * rcp(1 + 2^-S'), pack a->bf16 in place, PV via
// k-mapping-agnostic V B-fragments.
// ---------------------------------------------------------------------------
__global__ __launch_bounds__(256, 2) void dv_attn_kernel(
    const ushort* __restrict__ Qb, const ushort* __restrict__ Kb,
    const ushort* __restrict__ Vt, const ushort* __restrict__ KA,
    const ushort* __restrict__ QB, float* __restrict__ partial, int nch)
{
    __shared__ ushort lK[128 * 32];    // K tile, 16B-chunk rot swizzle
    __shared__ ushort lV[32 * 128];    // V^T tile, 8B-chunk XOR swizzle
    __shared__ ushort lKA[2][128 * 8]; // gate A-side aug, linear per half

    const int tid  = threadIdx.x;
    const int lane = tid & 63;
    const int wv   = tid >> 6;
    const int h2   = lane >> 5;
    const int l31  = lane & 31;
    const int rb   = blockIdx.x & 63;
    const int jg   = blockIdx.x >> 6;
    const int i0w  = rb * 128 + wv * 32;

    const ushort* qp = Qb + (size_t)(i0w + l31) * HID + h2 * 8;
    const short8 qf0 = *(const short8*)qp;
    const short8 qf1 = *(const short8*)(qp + 16);
    const short8 qaug = *(const short8*)&QB[((size_t)h2 * N + i0w + l31) * 8];

    f32x16 zacc, oacc;
#pragma unroll
    for (int r = 0; r < 16; ++r) { zacc[r] = 0.f; oacc[r] = 0.f; }
    float ssA = 0.f, ssB = 0.f;

    const int cA0 = (h2 + (l31 >> 1)) & 3;
    const int cA1 = (cA0 + 2) & 3;

    for (int ch = 0; ch < nch; ++ch) {
        const int j0 = (jg * nch + ch) << 7;
        __syncthreads();
        {
            int idx = tid;
#pragma unroll
            for (int rep = 0; rep < 2; ++rep, idx += 256) {
                int jr = idx >> 2, c = idx & 3;
                int c2 = (c + (jr >> 1)) & 3;
                *(uint4*)&lK[jr * 32 + c2 * 8] =
                    *(const uint4*)&Kb[(size_t)(j0 + jr) * HID + c * 8];
            }
            idx = tid;
#pragma unroll
            for (int rep = 0; rep < 4; ++rep, idx += 256) {
                int hh = idx >> 5, cc = idx & 31;
                int cs = cc ^ hh;
                *(uint2*)&lV[hh * 128 + cs * 4] =
                    *(const uint2*)&Vt[(size_t)hh * N + j0 + cc * 4];
            }
            {
                int half = tid >> 7, jj = tid & 127;
                *(uint4*)&lKA[half][jj * 8] =
                    *(const uint4*)&KA[((size_t)half * N + j0 + jj) * 8];
            }
        }
        __syncthreads();

#pragma unroll
        for (int t32 = 0; t32 < 4; ++t32) {
            const ushort* krow = &lK[(t32 * 32 + l31) * 32];
            short8 kf0 = *(const short8*)&krow[cA0 * 8];
            short8 kf1 = *(const short8*)&krow[cA1 * 8];
            f32x16 s = __builtin_amdgcn_mfma_f32_32x32x16_bf16(kf0, qf0, zacc, 0, 0, 0);
            s = __builtin_amdgcn_mfma_f32_32x32x16_bf16(kf1, qf1, s, 0, 0, 0);

            short8 kaug = *(const short8*)&lKA[h2][(t32 * 32 + l31) * 8];
            f32x16 gA = __builtin_amdgcn_mfma_f32_32x32x16_bf16(kaug, qaug, zacc, 0, 0, 0);

            uint32_t pk[8];
#pragma unroll
            for (int p = 0; p < 8; ++p) {
                // G = -D (clamped <= 0); a = 2^G / (1 + 2^-S')  — inf-free
                float g0 = fminf(gA[2 * p], 0.f);
                float g1 = fminf(gA[2 * p + 1], 0.f);
                float eg0 = __builtin_amdgcn_exp2f(g0);
                float es0 = __builtin_amdgcn_exp2f(-s[2 * p]);
                float a0  = eg0 * __builtin_amdgcn_rcpf(1.0f + es0);
                float eg1 = __builtin_amdgcn_exp2f(g1);
                float es1 = __builtin_amdgcn_exp2f(-s[2 * p + 1]);
                float a1  = eg1 * __builtin_amdgcn_rcpf(1.0f + es1);
                ssA += a0;
                ssB += a1;
                asm("v_cvt_pk_bf16_f32 %0, %1, %2" : "=v"(pk[p]) : "v"(a0), "v"(a1));
            }
            union BV { uint32_t u[4]; short8 v; };
            BV fa, fb;
            fa.u[0] = pk[0]; fa.u[1] = pk[1]; fa.u[2] = pk[2]; fa.u[3] = pk[3];
            fb.u[0] = pk[4]; fb.u[1] = pk[5]; fb.u[2] = pk[6]; fb.u[3] = pk[7];

            const ushort* vrow = &lV[l31 * 128];
            const int cb = t32 * 8 + h2;
            BV b0, b1;
            *(uint2*)&b0.u[0] = *(const uint2*)&vrow[((cb    ) ^ l31) * 4];
            *(uint2*)&b0.u[2] = *(const uint2*)&vrow[((cb + 2) ^ l31) * 4];
            *(uint2*)&b1.u[0] = *(const uint2*)&vrow[((cb + 4) ^ l31) * 4];
            *(uint2*)&b1.u[2] = *(const uint2*)&vrow[((cb + 6) ^ l31) * 4];

            oacc = __builtin_amdgcn_mfma_f32_32x32x16_bf16(fa.v, b0.v, oacc, 0, 0, 0);
            oacc = __builtin_amdgcn_mfma_f32_32x32x16_bf16(fb.v, b1.v, oacc, 0, 0, 0);
        }
    }

    float ssum = ssA + ssB;
    float sst = ssum + __shfl_xor(ssum, 32, 64);
    const size_t pbase = (size_t)jg * N * 33;
    if (lane < 32)
        partial[pbase + (size_t)(i0w + lane) * 33 + 32] = sst;
#pragma unroll
    for (int r = 0; r < 16; ++r) {
        int ir = (r & 3) + 8 * (r >> 2) + 4 * h2 + i0w;
        partial[pbase + (size_t)ir * 33 + l31] = oacc[r];
    }
}

// ---------------------------------------------------------------------------
// Kernel C: fused JG-reduce + epilogue with W2e-fused FFN2 (output =
// silu(Hn@W1+b1) @ W2e + b2e directly). 512 blocks x 256 thr; 16 rows/block,
// thread = (rl = tid&15 -> row) x (grp = tid>>4 -> 2 outputs / 8 FF dims).
// ---------------------------------------------------------------------------
__global__ __launch_bounds__(256) void dv_epilogue_kernel(
    const float* __restrict__ partial, int JG,
    const float* __restrict__ Wo, const float* __restrict__ bo,
    const float* __restrict__ ln_g, const float* __restrict__ ln_b,
    const float* __restrict__ W1, const float* __restrict__ b1,
    const float* __restrict__ W2e, const float* __restrict__ b2e,
    float* __restrict__ out)
{
    __shared__ float sr [33 * 16];   // [c][r]
    __shared__ float sHl[30 * 16];   // [o][r]
    __shared__ float sHn[30 * 16];
    __shared__ float shf[128 * 16];  // [f][r]
    __shared__ float sker[16 * 16];

    const int tid  = threadIdx.x;
    const int row0 = blockIdx.x * 16;

    // P1: reduce JG partials (row-contiguous reads)
    for (int idx = tid; idx < 33 * 16; idx += 256) {
        int r = idx / 33, c = idx - r * 33;
        const float* pp = partial + (size_t)(row0 + r) * 33 + c;
        float s = 0.f;
#pragma unroll 4
        for (int jg = 0; jg < JG; ++jg)
            s += pp[(size_t)jg * N * 33];
        sr[c * 16 + r] = s;
    }
    __syncthreads();                                    // B1

    const int rl  = tid & 15, grp = tid >> 4;
    const int o0  = grp * 2;
    const bool g15 = grp < 15;

    // P2: Wo GEMV + normalize
    if (g15) {
        float a0 = 0.f, a1 = 0.f;
#pragma unroll
        for (int h = 0; h < HID; ++h) {
            float2 w = *(const float2*)&Wo[h * D_OUT + o0];
            float sc = sr[h * 16 + rl];
            a0 = fmaf(sc, w.x, a0); a1 = fmaf(sc, w.y, a1);
        }
        float inv = __builtin_amdgcn_rcpf(sr[32 * 16 + rl] + 1e-8f);
        float2 bb = *(const float2*)&bo[o0];
        sHl[(o0    ) * 16 + rl] = fmaf(a0, inv, bb.x);
        sHl[(o0 + 1) * 16 + rl] = fmaf(a1, inv, bb.y);
    }
    __syncthreads();                                    // B2

    // P3: LayerNorm per row
    if (tid < 16) {
        const int r = tid;
        float mu = 0.f;
#pragma unroll
        for (int o = 0; o < D_OUT; ++o) mu += sHl[o * 16 + r];
        mu *= (1.0f / D_OUT);
        float var = 0.f;
#pragma unroll
        for (int o = 0; o < D_OUT; ++o) {
            float d = sHl[o * 16 + r] - mu; var = fmaf(d, d, var);
        }
        float rs = rsqrtf(var * (1.0f / D_OUT) + 1e-5f);
#pragma unroll
        for (int o = 0; o < D_OUT; ++o)
            sHn[o * 16 + r] = fmaf((sHl[o * 16 + r] - mu) * rs, ln_g[o], ln_b[o]);
    }
    __syncthreads();                                    // B3

    // P4: FFN1 + SiLU (grp's 8 FF dims)
    {
        const int f0 = grp * 8;
        float acc[8];
        float4 b4a = *(const float4*)&b1[f0];
        float4 b4b = *(const float4*)&b1[f0 + 4];
        acc[0] = b4a.x; acc[1] = b4a.y; acc[2] = b4a.z; acc[3] = b4a.w;
        acc[4] = b4b.x; acc[5] = b4b.y; acc[6] = b4b.z; acc[7] = b4b.w;
#pragma unroll
        for (int o = 0; o < D_OUT; ++o) {
            float4 wa = *(const float4*)&W1[o * FFD + f0];
            float4 wb = *(const float4*)&W1[o * FFD + f0 + 4];
            float hn = sHn[o * 16 + rl];
            acc[0] = fmaf(hn, wa.x, acc[0]); acc[1] = fmaf(hn, wa.y, acc[1]);
            acc[2] = fmaf(hn, wa.z, acc[2]); acc[3] = fmaf(hn, wa.w, acc[3]);
            acc[4] = fmaf(hn, wb.x, acc[4]); acc[5] = fmaf(hn, wb.y, acc[5]);
            acc[6] = fmaf(hn, wb.z, acc[6]); acc[7] = fmaf(hn, wb.w, acc[7]);
        }
        const float L2E = 1.4426950408889634f;
#pragma unroll
        for (int ff = 0; ff < 8; ++ff) {
            float a = acc[ff];
            shf[(f0 + ff) * 16 + rl] =
                a * __builtin_amdgcn_rcpf(1.0f + __builtin_amdgcn_exp2f(-a * L2E));
        }
    }
    __syncthreads();                                    // B4

    // P5: fused FFN2+We GEMV (W2e), output + ke partials
    if (g15) {
        float2 bb = *(const float2*)&b2e[o0];
        float a0 = bb.x, a1 = bb.y;
#pragma unroll 8
        for (int f = 0; f < FFD; ++f) {
            float2 w = *(const float2*)&W2e[f * D_OUT + o0];
            float hf = shf[f * 16 + rl];
            a0 = fmaf(hf, w.x, a0); a1 = fmaf(hf, w.y, a1);
        }
        float* op = out + (size_t)(row0 + rl) * ZC;
        op[o0] = a0; op[o0 + 1] = a1;
        sker[grp * 16 + rl] = fmaf(a0, a0, a1 * a1);
    }
    __syncthreads();                                    // B5

    if (tid < 16) {
        float ke = 0.f;
#pragma unroll
        for (int g = 0; g < 15; ++g) ke += sker[g * 16 + tid];
        float* op = out + (size_t)(row0 + tid) * ZC;
        op[30] = 0.f; op[31] = 0.f; op[32] = 0.f;
        op[33] = ke * (0.5f / D_OUT);
    }
}

// ---------------------------------------------------------------------------
extern "C" void kernel_launch(void* const* d_in, const int* in_sizes, int n_in,
                              void* d_out, int out_size, void* d_ws, size_t ws_size,
                              hipStream_t stream)
{
    const float* Z  = (const float*)d_in[1];
    const float* Wq = (const float*)d_in[2];
    const float* bq = (const float*)d_in[3];
    const float* Wk = (const float*)d_in[4];
    const float* bk = (const float*)d_in[5];
    const float* Wv = (const float*)d_in[6];
    const float* bv = (const float*)d_in[7];
    const float* Wo = (const float*)d_in[8];
    const float* bo = (const float*)d_in[9];
    const float* lg = (const float*)d_in[10];
    const float* lb = (const float*)d_in[11];
    const float* W1 = (const float*)d_in[12];
    const float* b1 = (const float*)d_in[13];
    const float* W2 = (const float*)d_in[14];
    const float* b2 = (const float*)d_in[15];
    const float* We = (const float*)d_in[16];
    const float* be = (const float*)d_in[17];
    float* out = (float*)d_out;

    ushort* Qb = (ushort*)d_ws;                  // N*32 bf16
    ushort* Kb = Qb + (size_t)N * HID;           // N*32 bf16
    ushort* Vt = Kb + (size_t)N * HID;           // [32][N] bf16
    ushort* KA = Vt + (size_t)N * HID;           // [2][N][8] bf16
    ushort* QB = KA + (size_t)N * 16;            // [2][N][8] bf16
    float* W2e = (float*)(QB + (size_t)N * 16);  // [128][30]
    float* b2e = W2e + FFD * D_OUT;              // [30] (+pad)
    float* partial = b2e + 32;                   // [JG][N][33] f32

    size_t base_bytes = (size_t)((char*)partial - (char*)d_ws);
    int JG = 16;
    while (JG > 1 && base_bytes + (size_t)JG * N * 33 * 4 > ws_size) JG >>= 1;
    int nch = N / (JG * 128);

    hipLaunchKernelGGL(dv_qkv_kernel, dim3((N * HID) / 256), dim3(256), 0, stream,
                       Z, Wq, bq, Wk, bk, Wv, bv, W2, We, b2, be,
                       Qb, Kb, Vt, KA, QB, W2e, b2e);
    hipLaunchKernelGGL(dv_attn_kernel, dim3(64 * JG), dim3(256), 0, stream,
                       Qb, Kb, Vt, KA, QB, partial, nch);
    hipLaunchKernelGGL(dv_epilogue_kernel, dim3(N / 16), dim3(256), 0, stream,
                       partial, JG, Wo, bo, lg, lb, W1, b1, W2e, b2e, out);
}

// Round 10
// 63.850 us; speedup vs baseline: 1.3193x; 1.0469x over previous
//
#include <hip/hip_runtime.h>
#include <hip/hip_bf16.h>

#define N      8192
#define D_IN   30
#define HID    32
#define D_OUT  30
#define FFD    128
#define ZC     34
#define JGC    16     // j-split groups

typedef __attribute__((ext_vector_type(8))) short short8;
typedef __attribute__((ext_vector_type(16))) float f32x16;

static __device__ __forceinline__ ushort f2bf(float x) {
    uint32_t u = __float_as_uint(x);
    uint32_t r = (u + 0x7fffu + ((u >> 16) & 1u)) >> 16;   // RTNE
    return (ushort)r;
}
static __device__ __forceinline__ float bf2f(ushort u) {
    return __uint_as_float(((uint32_t)u) << 16);
}

// ---------------------------------------------------------------------------
// Kernel A: QKV -> bf16 (Q pre-scaled log2e/sqrt(HID)); VWo^T = (V@Wo)^T in
// bf16 with row30 = 0, row31 = 1.0 (ones-column => PV MFMA col31 = rowsum);
// NEGATED split-bf16 gate tables (KA j-side, QB i-side) so gate MFMA = +D
// = d2/(2 sigma^2) * log2e; W2e = W2@We, b2e = b2@We + be.
// ---------------------------------------------------------------------------
__global__ __launch_bounds__(256) void dv_qkv_kernel(
    const float* __restrict__ Z,
    const float* __restrict__ Wq, const float* __restrict__ bq,
    const float* __restrict__ Wk, const float* __restrict__ bk,
    const float* __restrict__ Wv, const float* __restrict__ bv,
    const float* __restrict__ Wo,
    const float* __restrict__ W2, const float* __restrict__ We,
    const float* __restrict__ b2, const float* __restrict__ be,
    ushort* __restrict__ Qb, ushort* __restrict__ Kb,
    ushort* __restrict__ VWot, ushort* __restrict__ KA,
    ushort* __restrict__ QB, float* __restrict__ W2e, float* __restrict__ b2e)
{
    __shared__ ushort sv[8][33];
    const int t = blockIdx.x * 256 + threadIdx.x;
    const int i = t >> 5;
    const int h = t & 31;
    const float* z = Z + (size_t)i * ZC;

    float q = bq[h], k = bk[h], v = bv[h];
#pragma unroll
    for (int d = 0; d < D_IN; ++d) {
        float zf = z[d];
        q = fmaf(zf, Wq[d * HID + h], q);
        k = fmaf(zf, Wk[d * HID + h], k);
        v = fmaf(zf, Wv[d * HID + h], v);
    }
    const float QS = 0.17677669529663687f * 1.4426950408889634f; // log2e/sqrt(32)
    Qb[(size_t)i * HID + h] = f2bf(q * QS);
    Kb[(size_t)i * HID + h] = f2bf(k);
    sv[threadIdx.x >> 5][h] = f2bf(v);

    if (h == 0) {
        float p0 = z[D_IN], p1 = z[D_IN + 1], p2 = z[D_IN + 2];
        const float C2 = 1.4426950408889634f / 0.18f;   // log2e/(2*sigma^2)
        const float SC = sqrtf(2.0f * C2);
        float px = p0 * SC, py = p1 * SC, pz = p2 * SC;
        float w  = -C2 * (p0 * p0 + p1 * p1 + p2 * p2);
        ushort phx = f2bf(px), phy = f2bf(py), phz = f2bf(pz);
        ushort plx = f2bf(px - bf2f(phx));
        ushort ply = f2bf(py - bf2f(phy));
        ushort plz = f2bf(pz - bf2f(phz));
        ushort wh  = f2bf(w);
        ushort wl  = f2bf(w - bf2f(wh));
        // negate j-side (KA) => MFMA result = +D
        ushort nhx = phx ^ 0x8000, nhy = phy ^ 0x8000, nhz = phz ^ 0x8000;
        ushort nlx = plx ^ 0x8000, nly = ply ^ 0x8000, nlz = plz ^ 0x8000;
        ushort nwh = wh ^ 0x8000,  nwl = wl ^ 0x8000;
        const ushort one = 0x3F80, none = 0xBF80;
        ushort ka0[8] = {nwh, nwl, none, none, nhx, nhy, nhz, nhx};
        ushort ka1[8] = {nhy, nhz, nlx, nly, nlz, nlx, nly, nlz};
        ushort qb0[8] = {one, one, wh, wl, phx, phy, phz, plx};
        ushort qb1[8] = {ply, plz, phx, phy, phz, plx, ply, plz};
        *(uint4*)&KA[(size_t)i * 8]       = *(uint4*)ka0;
        *(uint4*)&KA[((size_t)N + i) * 8] = *(uint4*)ka1;
        *(uint4*)&QB[(size_t)i * 8]       = *(uint4*)qb0;
        *(uint4*)&QB[((size_t)N + i) * 8] = *(uint4*)qb1;
    }

    // W2e = W2 @ We  (+ b2e) over the first 15 blocks
    if (blockIdx.x < 15) {
        int idx = blockIdx.x * 256 + threadIdx.x;      // 0..3839
        int f = idx / 30, o = idx - f * 30;
        float acc = 0.f;
#pragma unroll
        for (int d = 0; d < D_OUT; ++d)
            acc = fmaf(W2[f * D_OUT + d], We[d * D_OUT + o], acc);
        W2e[idx] = acc;
        if (idx < D_OUT) {
            float a2 = be[idx];
#pragma unroll
            for (int d = 0; d < D_OUT; ++d)
                a2 = fmaf(b2[d], We[d * D_OUT + idx], a2);
            b2e[idx] = a2;
        }
    }

    __syncthreads();
    // VWo^T: row c (0..29) = (V@Wo) col c; row 30 = 0; row 31 = 1.0
    const int io = threadIdx.x >> 5, c = threadIdx.x & 31;
    const int ii = blockIdx.x * 8 + io;
    float val;
    if (c < 30) {
        float acc = 0.f;
#pragma unroll
        for (int hh = 0; hh < HID; ++hh)
            acc = fmaf(bf2f(sv[io][hh]), Wo[hh * D_OUT + c], acc);
        val = acc;
    } else {
        val = (c == 31) ? 1.0f : 0.f;
    }
    VWot[(size_t)c * N + ii] = f2bf(val);
}

// ---------------------------------------------------------------------------
// Kernel B: fused MFMA attention. Per 32x32 tile: 2 MFMA S' (swapped K,Q),
// 1 MFMA gate (+D), BOUNDED gate a = 2^(-max(D,0)) * rcp(1 + 2^-S')
// (every factor <= 1; the only inf touchpoint rcp(1+inf)=0 is R8-proven),
// pack in place, 2 MFMA PV with VWo^T (col31 ones => rowsum in output
// col 31). partial layout [N][JGC*32].
// ---------------------------------------------------------------------------
__global__ __launch_bounds__(256, 2) void dv_attn_kernel(
    const ushort* __restrict__ Qb, const ushort* __restrict__ Kb,
    const ushort* __restrict__ VWot, const ushort* __restrict__ KA,
    const ushort* __restrict__ QB, float* __restrict__ partial, int nch)
{
    __shared__ ushort lK[128 * 32];    // K tile, 16B-chunk rot swizzle
    __shared__ ushort lV[32 * 128];    // VWo^T tile, 8B-chunk XOR swizzle
    __shared__ ushort lKA[2][128 * 8]; // gate A-side aug

    const int tid  = threadIdx.x;
    const int lane = tid & 63;
    const int wv   = tid >> 6;
    const int h2   = lane >> 5;
    const int l31  = lane & 31;
    const int rb   = blockIdx.x & 63;
    const int jg   = blockIdx.x >> 6;
    const int i0w  = rb * 128 + wv * 32;

    const ushort* qp = Qb + (size_t)(i0w + l31) * HID + h2 * 8;
    const short8 qf0 = *(const short8*)qp;
    const short8 qf1 = *(const short8*)(qp + 16);
    const short8 qaug = *(const short8*)&QB[((size_t)h2 * N + i0w + l31) * 8];

    f32x16 zacc, oacc;
#pragma unroll
    for (int r = 0; r < 16; ++r) { zacc[r] = 0.f; oacc[r] = 0.f; }

    const int cA0 = (h2 + (l31 >> 1)) & 3;
    const int cA1 = (cA0 + 2) & 3;

    for (int ch = 0; ch < nch; ++ch) {
        const int j0 = (jg * nch + ch) << 7;
        __syncthreads();
        {
            int idx = tid;
#pragma unroll
            for (int rep = 0; rep < 2; ++rep, idx += 256) {
                int jr = idx >> 2, cc = idx & 3;
                int c2 = (cc + (jr >> 1)) & 3;
                *(uint4*)&lK[jr * 32 + c2 * 8] =
                    *(const uint4*)&Kb[(size_t)(j0 + jr) * HID + cc * 8];
            }
            idx = tid;
#pragma unroll
            for (int rep = 0; rep < 4; ++rep, idx += 256) {
                int hh = idx >> 5, cc = idx & 31;
                int cs = cc ^ hh;
                *(uint2*)&lV[hh * 128 + cs * 4] =
                    *(const uint2*)&VWot[(size_t)hh * N + j0 + cc * 4];
            }
            {
                int half = tid >> 7, jj = tid & 127;
                *(uint4*)&lKA[half][jj * 8] =
                    *(const uint4*)&KA[((size_t)half * N + j0 + jj) * 8];
            }
        }
        __syncthreads();

#pragma unroll
        for (int t32 = 0; t32 < 4; ++t32) {
            const ushort* krow = &lK[(t32 * 32 + l31) * 32];
            short8 kf0 = *(const short8*)&krow[cA0 * 8];
            short8 kf1 = *(const short8*)&krow[cA1 * 8];
            f32x16 s = __builtin_amdgcn_mfma_f32_32x32x16_bf16(kf0, qf0, zacc, 0, 0, 0);
            s = __builtin_amdgcn_mfma_f32_32x32x16_bf16(kf1, qf1, s, 0, 0, 0);

            short8 kaug = *(const short8*)&lKA[h2][(t32 * 32 + l31) * 8];
            f32x16 gA = __builtin_amdgcn_mfma_f32_32x32x16_bf16(kaug, qaug, zacc, 0, 0, 0);

            uint32_t pk[8];
#pragma unroll
            for (int p = 0; p < 8; ++p) {
                // a = 2^(-max(D,0)) * rcp(1 + 2^-S')  — all factors bounded
                float d0 = fmaxf(gA[2 * p], 0.f);
                float d1 = fmaxf(gA[2 * p + 1], 0.f);
                float eg0 = __builtin_amdgcn_exp2f(-d0);          // (0,1]
                float es0 = __builtin_amdgcn_exp2f(-s[2 * p]);    // [0,inf]
                float a0  = eg0 * __builtin_amdgcn_rcpf(1.0f + es0);
                float eg1 = __builtin_amdgcn_exp2f(-d1);
                float es1 = __builtin_amdgcn_exp2f(-s[2 * p + 1]);
                float a1  = eg1 * __builtin_amdgcn_rcpf(1.0f + es1);
                asm("v_cvt_pk_bf16_f32 %0, %1, %2" : "=v"(pk[p]) : "v"(a0), "v"(a1));
            }
            union BV { uint32_t u[4]; short8 v; };
            BV fa, fb;
            fa.u[0] = pk[0]; fa.u[1] = pk[1]; fa.u[2] = pk[2]; fa.u[3] = pk[3];
            fb.u[0] = pk[4]; fb.u[1] = pk[5]; fb.u[2] = pk[6]; fb.u[3] = pk[7];

            const ushort* vrow = &lV[l31 * 128];
            const int cb = t32 * 8 + h2;
            BV b0, b1;
            *(uint2*)&b0.u[0] = *(const uint2*)&vrow[((cb    ) ^ l31) * 4];
            *(uint2*)&b0.u[2] = *(const uint2*)&vrow[((cb + 2) ^ l31) * 4];
            *(uint2*)&b1.u[0] = *(const uint2*)&vrow[((cb + 4) ^ l31) * 4];
            *(uint2*)&b1.u[2] = *(const uint2*)&vrow[((cb + 6) ^ l31) * 4];

            oacc = __builtin_amdgcn_mfma_f32_32x32x16_bf16(fa.v, b0.v, oacc, 0, 0, 0);
            oacc = __builtin_amdgcn_mfma_f32_32x32x16_bf16(fb.v, b1.v, oacc, 0, 0, 0);
        }
    }

    // partial[i][jg*32 + c]: c<30 = raw H(pre-Wo-bias), c==31 = rowsum
#pragma unroll
    for (int r = 0; r < 16; ++r) {
        int ir = (r & 3) + 8 * (r >> 2) + 4 * h2 + i0w;
        partial[(size_t)ir * (JGC * 32) + jg * 32 + l31] = oacc[r];
    }
}

// ---------------------------------------------------------------------------
// Kernel C: streaming JG-reduce + epilogue (Wo already folded).
// 512 blocks x 256 thr; 16 rows/block; grp = tid>>4 (2 outputs / 8 FF dims).
// ---------------------------------------------------------------------------
__global__ __launch_bounds__(256) void dv_epilogue_kernel(
    const float* __restrict__ partial,
    const float* __restrict__ bo,
    const float* __restrict__ ln_g, const float* __restrict__ ln_b,
    const float* __restrict__ W1, const float* __restrict__ b1,
    const float* __restrict__ W2e, const float* __restrict__ b2e,
    float* __restrict__ out)
{
    __shared__ float sr [32 * 16];   // [c][r] reduced raw H + rowsum
    __shared__ float sHl[30 * 16];
    __shared__ float sHn[30 * 16];
    __shared__ float shf[128 * 16];
    __shared__ float sker[16 * 16];

    const int tid  = threadIdx.x;
    const int row0 = blockIdx.x * 16;

    // P1: contiguous streaming reduce over JGC chunks
#pragma unroll
    for (int rep = 0; rep < 2; ++rep) {
        int idx = tid + rep * 256;
        int r = idx >> 5, c = idx & 31;
        const float* pp = partial + (size_t)(row0 + r) * (JGC * 32) + c;
        float s = 0.f;
#pragma unroll
        for (int jg = 0; jg < JGC; ++jg)
            s += pp[jg * 32];
        sr[c * 16 + r] = s;
    }
    __syncthreads();                                    // B1

    const int rl  = tid & 15, grp = tid >> 4;
    const int o0  = grp * 2;
    const bool g15 = grp < 15;

    // P2: H = raw*inv + bo (Wo folded into attention)
    if (g15) {
        float inv = __builtin_amdgcn_rcpf(sr[31 * 16 + rl] + 1e-8f);
        float2 bb = *(const float2*)&bo[o0];
        sHl[(o0    ) * 16 + rl] = fmaf(sr[(o0    ) * 16 + rl], inv, bb.x);
        sHl[(o0 + 1) * 16 + rl] = fmaf(sr[(o0 + 1) * 16 + rl], inv, bb.y);
    }
    __syncthreads();                                    // B2

    // P3: LayerNorm per row
    if (tid < 16) {
        const int r = tid;
        float mu = 0.f;
#pragma unroll
        for (int o = 0; o < D_OUT; ++o) mu += sHl[o * 16 + r];
        mu *= (1.0f / D_OUT);
        float var = 0.f;
#pragma unroll
        for (int o = 0; o < D_OUT; ++o) {
            float d = sHl[o * 16 + r] - mu; var = fmaf(d, d, var);
        }
        float rs = rsqrtf(var * (1.0f / D_OUT) + 1e-5f);
#pragma unroll
        for (int o = 0; o < D_OUT; ++o)
            sHn[o * 16 + r] = fmaf((sHl[o * 16 + r] - mu) * rs, ln_g[o], ln_b[o]);
    }
    __syncthreads();                                    // B3

    // P4: FFN1 + SiLU (grp's 8 FF dims)
    {
        const int f0 = grp * 8;
        float acc[8];
        float4 b4a = *(const float4*)&b1[f0];
        float4 b4b = *(const float4*)&b1[f0 + 4];
        acc[0] = b4a.x; acc[1] = b4a.y; acc[2] = b4a.z; acc[3] = b4a.w;
        acc[4] = b4b.x; acc[5] = b4b.y; acc[6] = b4b.z; acc[7] = b4b.w;
#pragma unroll
        for (int o = 0; o < D_OUT; ++o) {
            float4 wa = *(const float4*)&W1[o * FFD + f0];
            float4 wb = *(const float4*)&W1[o * FFD + f0 + 4];
            float hn = sHn[o * 16 + rl];
            acc[0] = fmaf(hn, wa.x, acc[0]); acc[1] = fmaf(hn, wa.y, acc[1]);
            acc[2] = fmaf(hn, wa.z, acc[2]); acc[3] = fmaf(hn, wa.w, acc[3]);
            acc[4] = fmaf(hn, wb.x, acc[4]); acc[5] = fmaf(hn, wb.y, acc[5]);
            acc[6] = fmaf(hn, wb.z, acc[6]); acc[7] = fmaf(hn, wb.w, acc[7]);
        }
        const float L2E = 1.4426950408889634f;
#pragma unroll
        for (int ff = 0; ff < 8; ++ff) {
            float a = acc[ff];
            shf[(f0 + ff) * 16 + rl] =
                a * __builtin_amdgcn_rcpf(1.0f + __builtin_amdgcn_exp2f(-a * L2E));
        }
    }
    __syncthreads();                                    // B4

    // P5: fused FFN2+We GEMV (W2e), outputs + ke partials
    if (g15) {
        float2 bb = *(const float2*)&b2e[o0];
        float a0 = bb.x, a1 = bb.y;
#pragma unroll 8
        for (int f = 0; f < FFD; ++f) {
            float2 w = *(const float2*)&W2e[f * D_OUT + o0];
            float hf = shf[f * 16 + rl];
            a0 = fmaf(hf, w.x, a0); a1 = fmaf(hf, w.y, a1);
        }
        float* op = out + (size_t)(row0 + rl) * ZC;
        op[o0] = a0; op[o0 + 1] = a1;
        sker[grp * 16 + rl] = fmaf(a0, a0, a1 * a1);
    }
    __syncthreads();                                    // B5

    if (tid < 16) {
        float ke = 0.f;
#pragma unroll
        for (int g = 0; g < 15; ++g) ke += sker[g * 16 + tid];
        float* op = out + (size_t)(row0 + tid) * ZC;
        op[30] = 0.f; op[31] = 0.f; op[32] = 0.f;
        op[33] = ke * (0.5f / D_OUT);
    }
}

// ---------------------------------------------------------------------------
extern "C" void kernel_launch(void* const* d_in, const int* in_sizes, int n_in,
                              void* d_out, int out_size, void* d_ws, size_t ws_size,
                              hipStream_t stream)
{
    const float* Z  = (const float*)d_in[1];
    const float* Wq = (const float*)d_in[2];
    const float* bq = (const float*)d_in[3];
    const float* Wk = (const float*)d_in[4];
    const float* bk = (const float*)d_in[5];
    const float* Wv = (const float*)d_in[6];
    const float* bv = (const float*)d_in[7];
    const float* Wo = (const float*)d_in[8];
    const float* bo = (const float*)d_in[9];
    const float* lg = (const float*)d_in[10];
    const float* lb = (const float*)d_in[11];
    const float* W1 = (const float*)d_in[12];
    const float* b1 = (const float*)d_in[13];
    const float* W2 = (const float*)d_in[14];
    const float* b2 = (const float*)d_in[15];
    const float* We = (const float*)d_in[16];
    const float* be = (const float*)d_in[17];
    float* out = (float*)d_out;

    ushort* Qb   = (ushort*)d_ws;                 // N*32 bf16
    ushort* Kb   = Qb + (size_t)N * HID;          // N*32 bf16
    ushort* VWot = Kb + (size_t)N * HID;          // [32][N] bf16 (V@Wo)^T
    ushort* KA   = VWot + (size_t)N * HID;        // [2][N][8] bf16
    ushort* QB   = KA + (size_t)N * 16;           // [2][N][8] bf16
    float*  W2e  = (float*)(QB + (size_t)N * 16); // [128][30]
    float*  b2e  = W2e + FFD * D_OUT;             // [30] (+pad)
    float*  partial = b2e + 32;                   // [N][JGC*32] f32

    int nch = N / (JGC * 128);

    hipLaunchKernelGGL(dv_qkv_kernel, dim3((N * HID) / 256), dim3(256), 0, stream,
                       Z, Wq, bq, Wk, bk, Wv, bv, Wo, W2, We, b2, be,
                       Qb, Kb, VWot, KA, QB, W2e, b2e);
    hipLaunchKernelGGL(dv_attn_kernel, dim3(64 * JGC), dim3(256), 0, stream,
                       Qb, Kb, VWot, KA, QB, partial, nch);
    hipLaunchKernelGGL(dv_epilogue_kernel, dim3(N / 16), dim3(256), 0, stream,
                       partial, bo, lg, lb, W1, b1, W2e, b2e, out);
}